// Round 1
// baseline (89.814 us; speedup 1.0000x reference)
//
#include <hip/hip_runtime.h>
#include <hip/hip_bf16.h>

// TimeEmbedding: out[i, e] = W[e, elt[i]] + b[e]
//   elt: [B]    int32, values in [0, V)
//   W:   [E, V] float32 (row-major, so W[e, v] = W[e*V + v])
//   b:   [E]    float32
//   out: [B, E] float32
// B = 4096, E = 128, V = 100000.
//
// Layout: tid = i*E + e, so lane index tracks e -> coalesced out stores.
// W reads are a scatter/gather (stride V*4 = 400 KB across e) — unavoidable
// given W's [E, V] layout; W (51.2 MB) fits in L3 so repeats are absorbed.

#define EMB_DIM 128
#define NB_WORDS 100000
#define BATCH 4096

__global__ __launch_bounds__(256) void time_embedding_kernel(
    const int* __restrict__ elt,
    const float* __restrict__ W,
    const float* __restrict__ b,
    float* __restrict__ out)
{
    const int tid = blockIdx.x * blockDim.x + threadIdx.x;  // over B*E
    if (tid >= BATCH * EMB_DIM) return;
    const int e = tid & (EMB_DIM - 1);
    const int i = tid >> 7;  // / EMB_DIM
    const int v = elt[i];
    out[tid] = W[(size_t)e * NB_WORDS + v] + b[e];
}

extern "C" void kernel_launch(void* const* d_in, const int* in_sizes, int n_in,
                              void* d_out, int out_size, void* d_ws, size_t ws_size,
                              hipStream_t stream) {
    const int*   elt = (const int*)d_in[0];
    const float* W   = (const float*)d_in[1];
    const float* b   = (const float*)d_in[2];
    float*       out = (float*)d_out;

    const int total = BATCH * EMB_DIM;           // 524288
    const int block = 256;
    const int grid  = (total + block - 1) / block;  // 2048
    time_embedding_kernel<<<grid, block, 0, stream>>>(elt, W, b, out);
}

// Round 2
// 89.564 us; speedup vs baseline: 1.0028x; 1.0028x over previous
//
#include <hip/hip_runtime.h>
#include <hip/hip_bf16.h>

// TimeEmbedding: out[i, e] = W[e, elt[i]] + b[e]
//   elt: [B]    int32, values in [0, V)
//   W:   [E, V] float32 (row-major, W[e, v] = W[e*V + v])
//   b:   [E]    float32
//   out: [B, E] float32
// B = 4096, E = 128, V = 100000.
//
// R1: each thread handles 4 consecutive e for one i:
//   - 4 independent strided gather loads from W (ILP=4, latency overlap)
//   - one coalesced float4 store to out
//   - float4 bias load
// The W gather (stride 400 KB across e) is the unavoidable cost; W (51.2 MB)
// lives in L3 after first touch. Minimal traffic ≈ 25 MB gather + 2 MB store.

#define EMB_DIM 128
#define NB_WORDS 100000
#define BATCH 4096

__global__ __launch_bounds__(256) void time_embedding_kernel(
    const int* __restrict__ elt,
    const float* __restrict__ W,
    const float* __restrict__ b,
    float* __restrict__ out)
{
    // tid over B * (E/4) = 4096 * 32 = 131072
    const int tid = blockIdx.x * blockDim.x + threadIdx.x;
    const int q = tid & 31;          // which float4 of the row (0..31)
    const int i = tid >> 5;          // batch index
    const int e = q << 2;            // starting embedding dim (0,4,...,124)

    const int v = elt[i];            // 32 lanes share this address -> 1 request

    const size_t base = (size_t)e * NB_WORDS + v;
    // 4 independent gathers, stride NB_WORDS floats (400 KB) apart
    const float w0 = W[base];
    const float w1 = W[base + (size_t)NB_WORDS];
    const float w2 = W[base + (size_t)2 * NB_WORDS];
    const float w3 = W[base + (size_t)3 * NB_WORDS];

    const float4 bb = ((const float4*)b)[q];

    float4 r;
    r.x = w0 + bb.x;
    r.y = w1 + bb.y;
    r.z = w2 + bb.z;
    r.w = w3 + bb.w;

    ((float4*)out)[(size_t)i * 32 + q] = r;   // coalesced 16 B/lane store
}

extern "C" void kernel_launch(void* const* d_in, const int* in_sizes, int n_in,
                              void* d_out, int out_size, void* d_ws, size_t ws_size,
                              hipStream_t stream) {
    const int*   elt = (const int*)d_in[0];
    const float* W   = (const float*)d_in[1];
    const float* b   = (const float*)d_in[2];
    float*       out = (float*)d_out;

    const int total = BATCH * (EMB_DIM / 4);        // 131072 threads
    const int block = 256;
    const int grid  = (total + block - 1) / block;  // 512 blocks
    time_embedding_kernel<<<grid, block, 0, stream>>>(elt, W, b, out);
}